// Round 3
// baseline (893.476 us; speedup 1.0000x reference)
//
#include <hip/hip_runtime.h>
#include <hip/hip_bf16.h>

#define NEG 0.01f

using f32x4  = __attribute__((ext_vector_type(4))) float;
using bf16x8 = __attribute__((ext_vector_type(8))) short;

__device__ __forceinline__ unsigned short f2b(float f) {
  union { float f; unsigned int u; } v; v.f = f;
  unsigned int r = (v.u + 0x7fffu + ((v.u >> 16) & 1u)) >> 16;
  return (unsigned short)r;
}
__device__ __forceinline__ float b2f(unsigned int bits) {
  union { unsigned int u; float f; } v; v.u = bits << 16;
  return v.f;
}

__device__ __forceinline__ void gload16(const unsigned short* g, unsigned short* l) {
  __builtin_amdgcn_global_load_lds(
      (const __attribute__((address_space(1))) unsigned int*)g,
      (__attribute__((address_space(3))) unsigned int*)l, 16, 0, 0);
}

// ---- fp32 -> bf16 bulk convert (vectorized) ----
__global__ void k_cvt(const float* __restrict__ in, unsigned short* __restrict__ out, int n4) {
  int i = blockIdx.x * blockDim.x + threadIdx.x;
  int stride = gridDim.x * blockDim.x;
  for (; i < n4; i += stride) {
    float4 v = reinterpret_cast<const float4*>(in)[i];
    ushort4 o;
    o.x = f2b(v.x); o.y = f2b(v.y); o.z = f2b(v.z); o.w = f2b(v.w);
    reinterpret_cast<ushort4*>(out)[i] = o;
  }
}

// ---- triangular-masked weight convert.  anti=0: out[i][j] = (j>=i)?W[i][j]:0
//      anti=1 (flip folded in): out[i][k] = (H-1-k>=i)?W[i][H-1-k]:0 ----
__global__ void k_cvt_tri(const float* __restrict__ W, unsigned short* __restrict__ out, int anti) {
  const int H = 2048;
  int i = blockIdx.x;
  const float* wr = W + (size_t)i * H;
  unsigned short* orow = out + (size_t)i * H;
  if (!anti) {
    for (int j = threadIdx.x; j < H; j += blockDim.x) {
      float v = (j >= i) ? wr[j] : 0.f;
      orow[j] = f2b(v);
    }
  } else {
    for (int k = threadIdx.x; k < H; k += blockDim.x) {
      int j = H - 1 - k;
      float v = (j >= i) ? wr[j] : 0.f;
      orow[k] = f2b(v);
    }
  }
}

// ---- bf16 MFMA GEMM, C = lrelu(A @ B^T + bias) stored bf16.
//      m97 structure: 128x128 tile, 4 waves (2x2) of 64x64, BK=32,
//      global_load_lds width-16 staging, 2 barriers per K-step.
//      mode: 0=full K, 1=upper-tri (kstart=bcol), 2=anti (kend=K-bcol) ----
__launch_bounds__(256)
__global__ void k_gemm(const unsigned short* __restrict__ A, int lda,
                       const unsigned short* __restrict__ B, int ldb,
                       const float* __restrict__ bias,
                       unsigned short* __restrict__ C, int ldc,
                       int K, int mode) {
  __shared__ unsigned short As[128 * 32];
  __shared__ unsigned short Bs[128 * 32];
  const int tid  = threadIdx.x;
  const int w    = tid >> 6;
  const int lane = tid & 63;
  const int brow = blockIdx.x * 128;
  const int bcol = blockIdx.y * 128;
  int kstart = 0, kend = K;
  if (mode == 1) kstart = bcol;
  else if (mode == 2) kend = K - bcol;

  const int wm = w >> 1, wn = w & 1;
  f32x4 zero = {0.f, 0.f, 0.f, 0.f};
  f32x4 acc[4][4];
#pragma unroll
  for (int i = 0; i < 4; i++)
#pragma unroll
    for (int j = 0; j < 4; j++) acc[i][j] = zero;

  // staging: per call, a wave moves 16 rows x 32 cols (64 lanes x 16B)
  const int sr = lane >> 2;          // 0..15 row within wave's 16-row stripe
  const int sc = (lane & 3) * 8;     // 0,8,16,24 col
  const unsigned short* Abase = A + (size_t)(brow + w * 16 + sr) * lda + sc;
  const unsigned short* Bbase = B + (size_t)(bcol + w * 16 + sr) * ldb + sc;
  unsigned short* AsW = &As[(w * 16) * 32];
  unsigned short* BsW = &Bs[(w * 16) * 32];

  const int lrow = lane & 15;
  const int lk   = (lane >> 4) * 8;

  for (int kt = kstart; kt < kend; kt += 32) {
    gload16(Abase + kt,                       AsW);
    gload16(Abase + (size_t)64 * lda + kt,    AsW + 64 * 32);
    gload16(Bbase + kt,                       BsW);
    gload16(Bbase + (size_t)64 * ldb + kt,    BsW + 64 * 32);
    __syncthreads();   // compiler emits s_waitcnt vmcnt(0) before barrier

    bf16x8 af[4], bfr[4];
#pragma unroll
    for (int i = 0; i < 4; i++) {
      af[i]  = *reinterpret_cast<const bf16x8*>(&As[(wm * 64 + i * 16 + lrow) * 32 + lk]);
      bfr[i] = *reinterpret_cast<const bf16x8*>(&Bs[(wn * 64 + i * 16 + lrow) * 32 + lk]);
    }
#pragma unroll
    for (int i = 0; i < 4; i++)
#pragma unroll
      for (int j = 0; j < 4; j++)
        acc[i][j] = __builtin_amdgcn_mfma_f32_16x16x32_bf16(af[i], bfr[j], acc[i][j], 0, 0, 0);
    __syncthreads();
  }

  // epilogue: bias + leaky-relu + bf16 store
  const int orow0 = brow + wm * 64 + (lane >> 4) * 4;
  const int ocol0 = bcol + wn * 64 + (lane & 15);
#pragma unroll
  for (int j = 0; j < 4; j++) {
    int col = ocol0 + j * 16;
    float bv = bias[col];
#pragma unroll
    for (int i = 0; i < 4; i++) {
#pragma unroll
      for (int r = 0; r < 4; r++) {
        int row = orow0 + i * 16 + r;
        float v = acc[i][j][r] + bv;
        v = v > 0.f ? v : NEG * v;
        C[(size_t)row * ldc + col] = f2b(v);
      }
    }
  }
}

// ---- final layer: out[n,0..2] = A[n,:] @ ow[o,:] + ob.  A already lrelu'd bf16.
__global__ void k_out(const unsigned short* __restrict__ A,
                      const float* __restrict__ ow, const float* __restrict__ ob,
                      float* __restrict__ out) {
  const int H = 2048;
  int w = threadIdx.x >> 6, lane = threadIdx.x & 63;
  size_t n = (size_t)blockIdx.x * 4 + w;
  const unsigned short* a = A + n * H;
  float s0 = 0.f, s1 = 0.f, s2 = 0.f;
  for (int h0 = lane * 8; h0 < H; h0 += 512) {
    uint4 u = *reinterpret_cast<const uint4*>(&a[h0]);
    unsigned int uu[4] = {u.x, u.y, u.z, u.w};
#pragma unroll
    for (int q = 0; q < 4; q++) {
      int h = h0 + q * 2;
      float x0 = b2f(uu[q] & 0xffffu);
      float x1 = b2f(uu[q] >> 16);
      s0 += x0 * ow[h]         + x1 * ow[h + 1];
      s1 += x0 * ow[H + h]     + x1 * ow[H + h + 1];
      s2 += x0 * ow[2 * H + h] + x1 * ow[2 * H + h + 1];
    }
  }
#pragma unroll
  for (int off = 32; off > 0; off >>= 1) {
    s0 += __shfl_down(s0, off);
    s1 += __shfl_down(s1, off);
    s2 += __shfl_down(s2, off);
  }
  if (lane == 0) {
    out[n * 3 + 0] = s0 + ob[0];
    out[n * 3 + 1] = s1 + ob[1];
    out[n * 3 + 2] = s2 + ob[2];
  }
}

extern "C" void kernel_launch(void* const* d_in, const int* in_sizes, int n_in,
                              void* d_out, int out_size, void* d_ws, size_t ws_size,
                              hipStream_t stream) {
  const int N = 32768, H = 2048, INF_ = 64;
  const float* p      = (const float*)d_in[0];
  const float* init_w = (const float*)d_in[1];
  const float* init_b = (const float*)d_in[2];
  const float* w1     = (const float*)d_in[3];
  const float* b1     = (const float*)d_in[4];
  const float* w2     = (const float*)d_in[5];
  const float* b2     = (const float*)d_in[6];
  const float* w3     = (const float*)d_in[7];
  const float* b3     = (const float*)d_in[8];
  const float* ow     = (const float*)d_in[9];
  const float* ob     = (const float*)d_in[10];

  // ws-size-aware layout: fixed weight area + two chunked activation buffers
  char* wsb = (char*)d_ws;
  size_t off = 0;
  auto alloc = [&](size_t bytes) -> char* {
    char* q = wsb + off;
    off += (bytes + 255) & ~(size_t)255;
    return q;
  };
  unsigned short* pb  = (unsigned short*)alloc((size_t)N * INF_ * 2);
  unsigned short* iwb = (unsigned short*)alloc((size_t)H * INF_ * 2);
  unsigned short* w1m = (unsigned short*)alloc((size_t)H * H * 2);
  unsigned short* w2m = (unsigned short*)alloc((size_t)H * H * 2);
  unsigned short* w3m = (unsigned short*)alloc((size_t)H * H * 2);

  size_t remain = (ws_size > off) ? (ws_size - off) : 0;
  // two ping-pong buffers of Nc*H bf16 each
  long long ncll = (long long)(remain / ((size_t)H * 2 * 2));
  int Nc = (int)((ncll / 128) * 128);
  if (Nc > N) Nc = N;
  if (Nc < 128) return;  // ws too small for this design: leave d_out poisoned
                         // (clean absmax failure instead of a device fault)
  unsigned short* bufA = (unsigned short*)(wsb + off);
  unsigned short* bufB = bufA + (size_t)Nc * H;

  // one-time converts (weights + input)
  k_cvt<<<2048, 256, 0, stream>>>(p, pb, N * INF_ / 4);
  k_cvt<<<32,   256, 0, stream>>>(init_w, iwb, H * INF_ / 4);
  k_cvt_tri<<<H, 256, 0, stream>>>(w1, w1m, 0);
  k_cvt_tri<<<H, 256, 0, stream>>>(w2, w2m, 0);
  k_cvt_tri<<<H, 256, 0, stream>>>(w3, w3m, 1);

  for (int n0 = 0; n0 < N; n0 += Nc) {
    int nc = (N - n0 < Nc) ? (N - n0) : Nc;
    dim3 grid(nc / 128, H / 128);
    // layer 0: x0 = p @ init_w^T + init_b ; store lrelu(x0)
    k_gemm<<<grid, 256, 0, stream>>>(pb + (size_t)n0 * INF_, INF_, iwb, INF_, init_b,
                                     bufA, H, INF_, 0);
    // layer 1 (upper-tri)
    k_gemm<<<grid, 256, 0, stream>>>(bufA, H, w1m, H, b1, bufB, H, H, 1);
    // layer 2 (upper-tri; output kept unflipped — flip folded into w3m)
    k_gemm<<<grid, 256, 0, stream>>>(bufB, H, w2m, H, b2, bufA, H, H, 1);
    // layer 3 (anti-tri, pre-flipped weights)
    k_gemm<<<grid, 256, 0, stream>>>(bufA, H, w3m, H, b3, bufB, H, H, 2);
    // out head for this chunk
    k_out<<<nc / 4, 256, 0, stream>>>(bufB, ow, ob, (float*)d_out + (size_t)n0 * 3);
  }
}

// Round 4
// 859.494 us; speedup vs baseline: 1.0395x; 1.0395x over previous
//
#include <hip/hip_runtime.h>
#include <hip/hip_bf16.h>

#define NEG 0.01f

using f32x4  = __attribute__((ext_vector_type(4))) float;
using bf16x8 = __attribute__((ext_vector_type(8))) short;

__device__ __forceinline__ unsigned short f2b(float f) {
  union { float f; unsigned int u; } v; v.f = f;
  unsigned int r = (v.u + 0x7fffu + ((v.u >> 16) & 1u)) >> 16;
  return (unsigned short)r;
}
__device__ __forceinline__ float b2f(unsigned int bits) {
  union { unsigned int u; float f; } v; v.u = bits << 16;
  return v.f;
}

__device__ __forceinline__ void gload16(const unsigned short* g, unsigned short* l) {
  __builtin_amdgcn_global_load_lds(
      (const __attribute__((address_space(1))) unsigned int*)g,
      (__attribute__((address_space(3))) unsigned int*)l, 16, 0, 0);
}

// ---- fp32 -> bf16 bulk convert (vectorized) ----
__global__ void k_cvt(const float* __restrict__ in, unsigned short* __restrict__ out, int n4) {
  int i = blockIdx.x * blockDim.x + threadIdx.x;
  int stride = gridDim.x * blockDim.x;
  for (; i < n4; i += stride) {
    float4 v = reinterpret_cast<const float4*>(in)[i];
    ushort4 o;
    o.x = f2b(v.x); o.y = f2b(v.y); o.z = f2b(v.z); o.w = f2b(v.w);
    reinterpret_cast<ushort4*>(out)[i] = o;
  }
}

// ---- triangular-masked weight convert.  anti=0: out[i][j] = (j>=i)?W[i][j]:0
//      anti=1 (flip folded in): out[i][k] = (H-1-k>=i)?W[i][H-1-k]:0 ----
__global__ void k_cvt_tri(const float* __restrict__ W, unsigned short* __restrict__ out, int anti) {
  const int H = 2048;
  int i = blockIdx.x;
  const float* wr = W + (size_t)i * H;
  unsigned short* orow = out + (size_t)i * H;
  if (!anti) {
    for (int j = threadIdx.x; j < H; j += blockDim.x) {
      float v = (j >= i) ? wr[j] : 0.f;
      orow[j] = f2b(v);
    }
  } else {
    for (int k = threadIdx.x; k < H; k += blockDim.x) {
      int j = H - 1 - k;
      float v = (j >= i) ? wr[j] : 0.f;
      orow[k] = f2b(v);
    }
  }
}

// ---- bf16 MFMA GEMM, C = lrelu(A @ B^T + bias) stored bf16.
//      Tile 128(rows) x 256(cols), 512 threads = 8 waves (2 row x 4 col) of
//      64x64.  BK=32, global_load_lds w=16 staging, 2 barriers per K-step.
//      Grid is 1D, col-fastest, XCD-chunked swizzle so 8 consecutive logical
//      blocks (sharing one A row-panel) land on the same XCD -> A L2-hits.
//      mode: 0=full K, 1=upper-tri (kstart=bcol), 2=anti (kend=K-bcol) ----
__launch_bounds__(512)
__global__ void k_gemm(const unsigned short* __restrict__ A, int lda,
                       const unsigned short* __restrict__ B, int ldb,
                       const float* __restrict__ bias,
                       unsigned short* __restrict__ C, int ldc,
                       int K, int mode) {
  __shared__ unsigned short As[128 * 32];
  __shared__ unsigned short Bs[256 * 32];
  const int tid  = threadIdx.x;
  const int w    = tid >> 6;        // 0..7
  const int lane = tid & 63;

  // XCD-chunked bijective swizzle (nwg % 8 == 0 by construction)
  const int nwg = gridDim.x;
  const int q   = nwg >> 3;
  const int L   = blockIdx.x;
  const int logical = (L & 7) * q + (L >> 3);
  const int bx = logical & 7;       // col tile (8 tiles of 256 over H=2048)
  const int by = logical >> 3;      // row tile
  const int brow = by * 128;
  const int bcol = bx * 256;

  int kstart = 0, kend = K;
  if (mode == 1) kstart = bcol;
  else if (mode == 2) kend = K - bcol;

  const int wm = w >> 2;            // 0..1  (64-row stripe)
  const int wn = w & 3;             // 0..3  (64-col stripe)
  f32x4 zero = {0.f, 0.f, 0.f, 0.f};
  f32x4 acc[4][4];
#pragma unroll
  for (int i = 0; i < 4; i++)
#pragma unroll
    for (int j = 0; j < 4; j++) acc[i][j] = zero;

  // staging: per gload16 round, the 8 waves cover 128 rows x 32 cols
  const int sr = lane >> 2;          // 0..15 row within wave's 16-row stripe
  const int sc = (lane & 3) * 8;     // 0,8,16,24 col
  const unsigned short* Abase = A + (size_t)(brow + w * 16 + sr) * lda + sc;
  const unsigned short* Bbase = B + (size_t)(bcol + w * 16 + sr) * ldb + sc;
  unsigned short* AsW = &As[(w * 16) * 32];
  unsigned short* BsW = &Bs[(w * 16) * 32];

  const int lrow = lane & 15;
  const int lk   = (lane >> 4) * 8;

  for (int kt = kstart; kt < kend; kt += 32) {
    gload16(Abase + kt,                        AsW);
    gload16(Bbase + kt,                        BsW);
    gload16(Bbase + (size_t)128 * ldb + kt,    BsW + 128 * 32);
    __syncthreads();   // compiler emits s_waitcnt vmcnt(0) lgkmcnt(0) first

    bf16x8 af[4], bfr[4];
#pragma unroll
    for (int i = 0; i < 4; i++) {
      af[i]  = *reinterpret_cast<const bf16x8*>(&As[(wm * 64 + i * 16 + lrow) * 32 + lk]);
      bfr[i] = *reinterpret_cast<const bf16x8*>(&Bs[(wn * 64 + i * 16 + lrow) * 32 + lk]);
    }
#pragma unroll
    for (int i = 0; i < 4; i++)
#pragma unroll
      for (int j = 0; j < 4; j++)
        acc[i][j] = __builtin_amdgcn_mfma_f32_16x16x32_bf16(af[i], bfr[j], acc[i][j], 0, 0, 0);
    __syncthreads();
  }

  // epilogue: bias + leaky-relu + bf16 store
  const int orow0 = brow + wm * 64 + (lane >> 4) * 4;
  const int ocol0 = bcol + wn * 64 + (lane & 15);
#pragma unroll
  for (int j = 0; j < 4; j++) {
    int col = ocol0 + j * 16;
    float bv = bias[col];
#pragma unroll
    for (int i = 0; i < 4; i++) {
#pragma unroll
      for (int r = 0; r < 4; r++) {
        int row = orow0 + i * 16 + r;
        float v = acc[i][j][r] + bv;
        v = v > 0.f ? v : NEG * v;
        C[(size_t)row * ldc + col] = f2b(v);
      }
    }
  }
}

// ---- final layer: out[n,0..2] = A[n,:] @ ow[o,:] + ob.  A already lrelu'd bf16.
__global__ void k_out(const unsigned short* __restrict__ A,
                      const float* __restrict__ ow, const float* __restrict__ ob,
                      float* __restrict__ out) {
  const int H = 2048;
  int w = threadIdx.x >> 6, lane = threadIdx.x & 63;
  size_t n = (size_t)blockIdx.x * 4 + w;
  const unsigned short* a = A + n * H;
  float s0 = 0.f, s1 = 0.f, s2 = 0.f;
  for (int h0 = lane * 8; h0 < H; h0 += 512) {
    uint4 u = *reinterpret_cast<const uint4*>(&a[h0]);
    unsigned int uu[4] = {u.x, u.y, u.z, u.w};
#pragma unroll
    for (int q = 0; q < 4; q++) {
      int h = h0 + q * 2;
      float x0 = b2f(uu[q] & 0xffffu);
      float x1 = b2f(uu[q] >> 16);
      s0 += x0 * ow[h]         + x1 * ow[h + 1];
      s1 += x0 * ow[H + h]     + x1 * ow[H + h + 1];
      s2 += x0 * ow[2 * H + h] + x1 * ow[2 * H + h + 1];
    }
  }
#pragma unroll
  for (int off = 32; off > 0; off >>= 1) {
    s0 += __shfl_down(s0, off);
    s1 += __shfl_down(s1, off);
    s2 += __shfl_down(s2, off);
  }
  if (lane == 0) {
    out[n * 3 + 0] = s0 + ob[0];
    out[n * 3 + 1] = s1 + ob[1];
    out[n * 3 + 2] = s2 + ob[2];
  }
}

extern "C" void kernel_launch(void* const* d_in, const int* in_sizes, int n_in,
                              void* d_out, int out_size, void* d_ws, size_t ws_size,
                              hipStream_t stream) {
  const int N = 32768, H = 2048, INF_ = 64;
  const float* p      = (const float*)d_in[0];
  const float* init_w = (const float*)d_in[1];
  const float* init_b = (const float*)d_in[2];
  const float* w1     = (const float*)d_in[3];
  const float* b1     = (const float*)d_in[4];
  const float* w2     = (const float*)d_in[5];
  const float* b2     = (const float*)d_in[6];
  const float* w3     = (const float*)d_in[7];
  const float* b3     = (const float*)d_in[8];
  const float* ow     = (const float*)d_in[9];
  const float* ob     = (const float*)d_in[10];

  // ws-size-aware layout: fixed weight area + two chunked activation buffers
  char* wsb = (char*)d_ws;
  size_t off = 0;
  auto alloc = [&](size_t bytes) -> char* {
    char* q = wsb + off;
    off += (bytes + 255) & ~(size_t)255;
    return q;
  };
  unsigned short* pb  = (unsigned short*)alloc((size_t)N * INF_ * 2);
  unsigned short* iwb = (unsigned short*)alloc((size_t)H * INF_ * 2);
  unsigned short* w1m = (unsigned short*)alloc((size_t)H * H * 2);
  unsigned short* w2m = (unsigned short*)alloc((size_t)H * H * 2);
  unsigned short* w3m = (unsigned short*)alloc((size_t)H * H * 2);

  size_t remain = (ws_size > off) ? (ws_size - off) : 0;
  // two ping-pong buffers of Nc*H bf16 each
  long long ncll = (long long)(remain / ((size_t)H * 2 * 2));
  int Nc = (int)((ncll / 128) * 128);
  if (Nc > N) Nc = N;
  if (Nc < 128) return;  // ws too small for this design: leave d_out poisoned

  unsigned short* bufA = (unsigned short*)(wsb + off);
  unsigned short* bufB = bufA + (size_t)Nc * H;

  // one-time converts (weights + input)
  k_cvt<<<2048, 256, 0, stream>>>(p, pb, N * INF_ / 4);
  k_cvt<<<32,   256, 0, stream>>>(init_w, iwb, H * INF_ / 4);
  k_cvt_tri<<<H, 256, 0, stream>>>(w1, w1m, 0);
  k_cvt_tri<<<H, 256, 0, stream>>>(w2, w2m, 0);
  k_cvt_tri<<<H, 256, 0, stream>>>(w3, w3m, 1);

  for (int n0 = 0; n0 < N; n0 += Nc) {
    int nc = (N - n0 < Nc) ? (N - n0) : Nc;
    int nblk = (H / 256) * (nc / 128);   // 1D grid, multiple of 8
    // layer 0: x0 = p @ init_w^T + init_b ; store lrelu(x0)
    k_gemm<<<nblk, 512, 0, stream>>>(pb + (size_t)n0 * INF_, INF_, iwb, INF_, init_b,
                                     bufA, H, INF_, 0);
    // layer 1 (upper-tri)
    k_gemm<<<nblk, 512, 0, stream>>>(bufA, H, w1m, H, b1, bufB, H, H, 1);
    // layer 2 (upper-tri; output kept unflipped — flip folded into w3m)
    k_gemm<<<nblk, 512, 0, stream>>>(bufB, H, w2m, H, b2, bufA, H, H, 1);
    // layer 3 (anti-tri, pre-flipped weights)
    k_gemm<<<nblk, 512, 0, stream>>>(bufA, H, w3m, H, b3, bufB, H, H, 2);
    // out head for this chunk
    k_out<<<nc / 4, 256, 0, stream>>>(bufB, ow, ob, (float*)d_out + (size_t)n0 * 3);
  }
}